// Round 9
// baseline (233.689 us; speedup 1.0000x reference)
//
#include <hip/hip_runtime.h>
#include <hip/hip_bf16.h>
#include <hip/hip_cooperative_groups.h>

namespace cg = cooperative_groups;

// FourierResistor: B=8, N=4096, d=128, H=4, fp32 in/out.
// sum-minus-self decomposition:
//   f[k,b,n,d]  = S[k,b,d] - xe[k,b,n,d],  S = sum_n xe
//   inv[b,n,h,d]= (T[b,h,d] - rfe[b,n,h,d]) / N,  T = sum_n rfe
// Pipeline (4 dispatches):
//   K0 prep  : Wlt,Wphi,Wf1,Wf2 -> bf16 (224 KB, once)
//   K1 fused : x1b = bf16(x@Wlt^T); S-partials -> PS; xs += pos;
//              phi8 = fp8e4m3((x1+pos)@Wphi^T+b) over 4 col tiles
//   K2 coop  : finS -> grid.sync -> reduceT partials -> grid.sync -> finT
//              (cooperative kernel, 512 blocks, replaces 3 dispatches)
//   K3       : fused comb MLP + LN -> LDS -> relu(mn@Wf1^T+b1)@Wf2^T+b2 -> out

#define DEV __device__ __forceinline__

typedef __attribute__((ext_vector_type(8))) short bf16x8;
typedef __attribute__((ext_vector_type(4))) float f32x4;

constexpr int Bb = 8, Nn = 4096;
constexpr int BN = Bb * Nn;     // 32768
constexpr int LDP = 136;        // padded LDS pitch in bf16 elems (272 B)
constexpr int P8  = 144;        // byte pitch for fp8 restage (16B-aligned)

union U8 { ushort u[8]; uint4 v; };

static DEV ushort f2bf(float f) {
    __hip_bfloat16 h = __float2bfloat16(f);
    return *reinterpret_cast<unsigned short*>(&h);
}
static DEV float bf2f(ushort u) {
    return __bfloat162float(*reinterpret_cast<const __hip_bfloat16*>(&u));
}
// native gfx950 OCP-e4m3 converts (1 VALU op each)
static DEV unsigned char f2fp8(float f) {
    return (unsigned char)(__builtin_amdgcn_cvt_pk_fp8_f32(f, f, 0u, false) & 0xff);
}

// ---------------------------------------------------------------------------
// K0: pre-convert weights fp32 -> bf16 (Wlt 16K | Wphi 64K | Wf1 16K | Wf2 16K)
// 56 blocks x 256 thr x 8 elems.
// ---------------------------------------------------------------------------
__global__ __launch_bounds__(256) void k_prep(
    const float* __restrict__ Wlt, const float* __restrict__ Wphi,
    const float* __restrict__ Wf1, const float* __restrict__ Wf2,
    ushort* __restrict__ wbLt, ushort* __restrict__ wbPhi,
    ushort* __restrict__ wbF1, ushort* __restrict__ wbF2)
{
    int bx = blockIdx.x;
    const float* src; ushort* dst; int off;
    if (bx < 8)       { src = Wlt;  dst = wbLt;  off = bx * 2048; }
    else if (bx < 40) { src = Wphi; dst = wbPhi; off = (bx - 8) * 2048; }
    else if (bx < 48) { src = Wf1;  dst = wbF1;  off = (bx - 40) * 2048; }
    else              { src = Wf2;  dst = wbF2;  off = (bx - 48) * 2048; }
    int e = off + threadIdx.x * 8;
    float4 a = *reinterpret_cast<const float4*>(src + e);
    float4 b = *reinterpret_cast<const float4*>(src + e + 4);
    U8 u;
    u.u[0] = f2bf(a.x); u.u[1] = f2bf(a.y); u.u[2] = f2bf(a.z); u.u[3] = f2bf(a.w);
    u.u[4] = f2bf(b.x); u.u[5] = f2bf(b.y); u.u[6] = f2bf(b.z); u.u[7] = f2bf(b.w);
    *reinterpret_cast<uint4*>(dst + e) = u.v;
}

// ---------------------------------------------------------------------------
// K1: fused x-GEMM + S-partials + phi-GEMM. W inputs are pre-converted bf16.
// 256 thr, 64-row tile. LDS: xs 17KB + wsl 34KB + aux 9KB = 60KB.
// ---------------------------------------------------------------------------
__global__ __launch_bounds__(256) void k_fused1(
    const float* __restrict__ X, const ushort* __restrict__ wbLt,
    const ushort* __restrict__ wbPhi, const float* __restrict__ bphi,
    const float* __restrict__ pos, ushort* __restrict__ x1b,
    unsigned char* __restrict__ phi8, float* __restrict__ PS)
{
    __shared__ __align__(16) ushort xs[64 * LDP];        // 17408 B
    __shared__ __align__(16) ushort wsl[128 * LDP];      // 34816 B
    __shared__ __align__(16) unsigned char aux[64 * P8]; // 9216 B (red | p8)
    float (*red)[2][128] = reinterpret_cast<float (*)[2][128]>(aux);
    unsigned char* p8 = aux;

    const int t = threadIdx.x;
    const int row0 = blockIdx.x * 64;
    const int w = t >> 6, l = t & 63;
    const int lr = l & 15;
    const int lk = (l >> 4) * 8;

    // ---- stage X tile (f32 -> bf16) ----
    #pragma unroll
    for (int i = 0; i < 4; ++i) {
        int e = t + i * 256, r = e >> 4, c = (e & 15) * 8;
        const float* p = X + (size_t)(row0 + r) * 128 + c;
        float4 a = *reinterpret_cast<const float4*>(p);
        float4 b = *reinterpret_cast<const float4*>(p + 4);
        U8 u;
        u.u[0] = f2bf(a.x); u.u[1] = f2bf(a.y); u.u[2] = f2bf(a.z); u.u[3] = f2bf(a.w);
        u.u[4] = f2bf(b.x); u.u[5] = f2bf(b.y); u.u[6] = f2bf(b.z); u.u[7] = f2bf(b.w);
        *reinterpret_cast<uint4*>(xs + r * LDP + c) = u.v;
    }
    // ---- stage Wlt (bf16, direct copy) ----
    #pragma unroll
    for (int i = 0; i < 8; ++i) {
        int e = t + i * 256, r = e >> 4, c = (e & 15) * 8;
        uint4 v = *reinterpret_cast<const uint4*>(wbLt + (size_t)r * 128 + c);
        *reinterpret_cast<uint4*>(wsl + r * LDP + c) = v;
    }
    __syncthreads();

    // ---- MFMA: x1 = x @ Wlt^T ----
    {
        f32x4 acc[8];
        #pragma unroll
        for (int cf = 0; cf < 8; ++cf) acc[cf] = f32x4{0.f, 0.f, 0.f, 0.f};
        #pragma unroll
        for (int ks = 0; ks < 4; ++ks) {
            bf16x8 a = *reinterpret_cast<const bf16x8*>(xs + (w * 16 + lr) * LDP + ks * 32 + lk);
            #pragma unroll
            for (int cf = 0; cf < 8; ++cf) {
                bf16x8 b = *reinterpret_cast<const bf16x8*>(wsl + (cf * 16 + lr) * LDP + ks * 32 + lk);
                acc[cf] = __builtin_amdgcn_mfma_f32_16x16x32_bf16(a, b, acc[cf], 0, 0, 0);
            }
        }
        __syncthreads();  // xs reads done

        // restage x1 into xs (bf16); C/D layout: col=lane&15, row=(lane>>4)*4+reg
        #pragma unroll
        for (int cf = 0; cf < 8; ++cf) {
            int col = cf * 16 + lr;
            #pragma unroll
            for (int reg = 0; reg < 4; ++reg) {
                int rl = w * 16 + (l >> 4) * 4 + reg;
                xs[rl * LDP + col] = f2bf(acc[cf][reg]);
            }
        }
    }
    __syncthreads();

    // ---- phase A: store x1b (coalesced) + S-partial column reduce from xs ----
    #pragma unroll
    for (int i = 0; i < 4; ++i) {
        int e = t + i * 256, r = e >> 4, c = (e & 15) * 8;
        uint4 v = *reinterpret_cast<const uint4*>(xs + r * LDP + c);
        *reinterpret_cast<uint4*>(x1b + (size_t)(row0 + r) * 128 + c) = v;
    }
    {
        int c2 = t & 63, g = t >> 6;
        float a0e = 0.f, a1e = 0.f, a0o = 0.f, a1o = 0.f;
        #pragma unroll 4
        for (int i = 0; i < 16; ++i) {
            int r = g * 16 + i;
            int n = (row0 + r) & (Nn - 1);
            unsigned int v = *reinterpret_cast<const unsigned int*>(xs + r * LDP + 2 * c2);
            float lo = bf2f((ushort)(v & 0xffff));
            float hi = bf2f((ushort)(v >> 16));
            float2 p = *reinterpret_cast<const float2*>(pos + (size_t)n * 128 + 2 * c2);
            a0e += lo * p.y; a1e += lo * p.x;   // cols 2c2, 2c2+1 share (s,c)
            a0o += hi * p.y; a1o += hi * p.x;
        }
        red[g][0][2 * c2] = a0e; red[g][0][2 * c2 + 1] = a0o;
        red[g][1][2 * c2] = a1e; red[g][1][2 * c2 + 1] = a1o;
    }
    __syncthreads();

    // ---- phase B: PS write (reads red) + xs += pos (in place) ----
    {
        int half = t >> 7, col = t & 127;
        float s = red[0][half][col] + red[1][half][col] + red[2][half][col] + red[3][half][col];
        PS[(size_t)blockIdx.x * 256 + t] = s;
    }
    #pragma unroll
    for (int i = 0; i < 4; ++i) {
        int e = t + i * 256, r = e >> 4, c = (e & 15) * 8;
        U8 u;
        u.v = *reinterpret_cast<const uint4*>(xs + r * LDP + c);
        int n = (row0 + r) & (Nn - 1);
        const float* q = pos + (size_t)n * 128 + c;
        float4 pa = *reinterpret_cast<const float4*>(q);
        float4 pb = *reinterpret_cast<const float4*>(q + 4);
        u.u[0] = f2bf(bf2f(u.u[0]) + pa.x);
        u.u[1] = f2bf(bf2f(u.u[1]) + pa.y);
        u.u[2] = f2bf(bf2f(u.u[2]) + pa.z);
        u.u[3] = f2bf(bf2f(u.u[3]) + pa.w);
        u.u[4] = f2bf(bf2f(u.u[4]) + pb.x);
        u.u[5] = f2bf(bf2f(u.u[5]) + pb.y);
        u.u[6] = f2bf(bf2f(u.u[6]) + pb.z);
        u.u[7] = f2bf(bf2f(u.u[7]) + pb.w);
        *reinterpret_cast<uint4*>(xs + r * LDP + c) = u.v;
    }

    // ---- phi loop: 4 col tiles of Wphi (bf16); p8 aliases red (red dead) ----
    for (int jt = 0; jt < 4; ++jt) {
        __syncthreads();   // wsl free / p8 of jt-1 encoded / phase B done
        {
            const ushort* Wt = wbPhi + (size_t)jt * 128 * 128;
            #pragma unroll
            for (int i = 0; i < 8; ++i) {
                int e = t + i * 256, r = e >> 4, c = (e & 15) * 8;
                uint4 v = *reinterpret_cast<const uint4*>(Wt + (size_t)r * 128 + c);
                *reinterpret_cast<uint4*>(wsl + r * LDP + c) = v;
            }
            if (jt > 0) {
                #pragma unroll
                for (int i = 0; i < 2; ++i) {
                    int e = t + i * 256, r = e >> 3, c = (e & 7) * 16;
                    uint4 v = *reinterpret_cast<const uint4*>(p8 + r * P8 + c);
                    *reinterpret_cast<uint4*>(phi8 + (size_t)(row0 + r) * 512 + (jt - 1) * 128 + c) = v;
                }
            }
        }
        __syncthreads();

        f32x4 acc[8];
        #pragma unroll
        for (int cf = 0; cf < 8; ++cf) acc[cf] = f32x4{0.f, 0.f, 0.f, 0.f};
        #pragma unroll
        for (int ks = 0; ks < 4; ++ks) {
            bf16x8 a = *reinterpret_cast<const bf16x8*>(xs + (w * 16 + lr) * LDP + ks * 32 + lk);
            #pragma unroll
            for (int cf = 0; cf < 8; ++cf) {
                bf16x8 b = *reinterpret_cast<const bf16x8*>(wsl + (cf * 16 + lr) * LDP + ks * 32 + lk);
                acc[cf] = __builtin_amdgcn_mfma_f32_16x16x32_bf16(a, b, acc[cf], 0, 0, 0);
            }
        }
        #pragma unroll
        for (int cf = 0; cf < 8; ++cf) {
            int col = cf * 16 + lr;
            float bv = bphi[jt * 128 + col];
            #pragma unroll
            for (int reg = 0; reg < 4; ++reg) {
                int rl = w * 16 + (l >> 4) * 4 + reg;
                p8[rl * P8 + col] = f2fp8(acc[cf][reg] + bv);
            }
        }
    }
    __syncthreads();
    #pragma unroll
    for (int i = 0; i < 2; ++i) {
        int e = t + i * 256, r = e >> 3, c = (e & 7) * 16;
        uint4 v = *reinterpret_cast<const uint4*>(p8 + r * P8 + c);
        *reinterpret_cast<uint4*>(phi8 + (size_t)(row0 + r) * 512 + 3 * 128 + c) = v;
    }
}

// ---------------------------------------------------------------------------
// K2: cooperative finS -> reduceT -> finT. 512 blocks x 256 thr.
// ---------------------------------------------------------------------------
__global__ __launch_bounds__(256) void k_coop_ST(
    const ushort* __restrict__ x1b, const unsigned char* __restrict__ phi8,
    const float* __restrict__ pos, const float* __restrict__ PS,
    float* __restrict__ S0, float* __restrict__ S1,
    float* __restrict__ PT, float* __restrict__ T)
{
    cg::grid_group grid = cg::this_grid();

    // ---- P0: finS — wave per output, 2048 outputs over 512 blocks x 4 waves
    {
        int idx = blockIdx.x * 4 + (threadIdx.x >> 6);   // 0..2047
        int lane = threadIdx.x & 63;
        int b = idx >> 8, tcol = idx & 255;
        float s = PS[(size_t)(b * 64 + lane) * 256 + tcol];
        #pragma unroll
        for (int off = 32; off; off >>= 1) s += __shfl_xor(s, off);
        if (lane == 0) {
            if (tcol < 128) S0[b * 128 + tcol] = s;
            else            S1[b * 128 + (tcol - 128)] = s;
        }
    }
    __threadfence();
    grid.sync();

    // ---- P1: reduceT partials (same geometry as standalone version) ----
    {
        int b = blockIdx.x >> 6, c64 = blockIdx.x & 63;
        int rr = threadIdx.x >> 5, d0 = (threadIdx.x & 31) * 4;
        float4 S0v = *reinterpret_cast<const float4*>(S0 + b * 128 + d0);
        float4 S1v = *reinterpret_cast<const float4*>(S1 + b * 128 + d0);
        float S0a[4] = {S0v.x, S0v.y, S0v.z, S0v.w};
        float S1a[4] = {S1v.x, S1v.y, S1v.z, S1v.w};
        float acc[4][4];
        #pragma unroll
        for (int h = 0; h < 4; ++h)
            #pragma unroll
            for (int j = 0; j < 4; ++j) acc[h][j] = 0.f;

        #pragma unroll 2
        for (int i = 0; i < 8; ++i) {
            int n = c64 * 64 + i * 8 + rr;
            size_t r = (size_t)b * Nn + n;
            ushort4 xv4 = *reinterpret_cast<const ushort4*>(x1b + r * 128 + d0);
            float4 p = *reinterpret_cast<const float4*>(pos + (size_t)n * 128 + d0);
            float xv[4] = {bf2f(xv4.x), bf2f(xv4.y), bf2f(xv4.z), bf2f(xv4.w)};
            float cc[4] = {p.y, p.y, p.w, p.w};
            float ss[4] = {p.x, p.x, p.z, p.z};
            float fec[4], fn[4];
            #pragma unroll
            for (int j = 0; j < 4; ++j) {
                float f0 = S0a[j] - xv[j] * cc[j];
                float f1 = xv[j] * ss[j] - S1a[j];
                fn[j] = sqrtf(f0 * f0 + f1 * f1);
                fec[j] = f0 * cc[j] - f1 * ss[j];
            }
            #pragma unroll
            for (int h = 0; h < 4; ++h) {
                unsigned int pv = *reinterpret_cast<const unsigned int*>(phi8 + r * 512 + h * 128 + d0);
                float ph0 = __builtin_amdgcn_cvt_f32_fp8(pv, 0);
                float ph1 = __builtin_amdgcn_cvt_f32_fp8(pv, 1);
                float ph2 = __builtin_amdgcn_cvt_f32_fp8(pv, 2);
                float ph3 = __builtin_amdgcn_cvt_f32_fp8(pv, 3);
                acc[h][0] += fmaxf(0.f, fminf(1.f, fn[0] - ph0)) * fec[0];
                acc[h][1] += fmaxf(0.f, fminf(1.f, fn[1] - ph1)) * fec[1];
                acc[h][2] += fmaxf(0.f, fminf(1.f, fn[2] - ph2)) * fec[2];
                acc[h][3] += fmaxf(0.f, fminf(1.f, fn[3] - ph3)) * fec[3];
            }
        }
        __shared__ float red[8][512];
        #pragma unroll
        for (int h = 0; h < 4; ++h)
            #pragma unroll
            for (int j = 0; j < 4; ++j) red[rr][h * 128 + d0 + j] = acc[h][j];
        __syncthreads();
        int tt = threadIdx.x;
        #pragma unroll
        for (int q = 0; q < 2; ++q) {
            int idx = tt + q * 256;
            float s = 0.f;
            #pragma unroll
            for (int k = 0; k < 8; ++k) s += red[k][idx];
            PT[(size_t)blockIdx.x * 512 + idx] = s;
        }
    }
    __threadfence();
    grid.sync();

    // ---- P2: finT — half-wave per output, 4096 outputs over 512 blocks x 8
    {
        int o = threadIdx.x >> 5, ll = threadIdx.x & 31;
        int idx = blockIdx.x * 8 + o;    // 0..4095
        int b = idx >> 9, lo = idx & 511;
        float s = PT[(size_t)b * 32768 + ll * 512 + lo]
                + PT[(size_t)b * 32768 + (ll + 32) * 512 + lo];
        #pragma unroll
        for (int off = 16; off; off >>= 1) s += __shfl_xor(s, off);
        if (ll == 0) T[idx] = s;
    }
}

// ---------------------------------------------------------------------------
// K3: fused comb+LN+FFN. Wf1/Wf2 pre-converted bf16.
// ---------------------------------------------------------------------------
__global__ __launch_bounds__(256) void k_comb_ffn(
    const ushort* __restrict__ x1b, const unsigned char* __restrict__ phi8,
    const float* __restrict__ pos, const float* __restrict__ S0,
    const float* __restrict__ S1, const float* __restrict__ T,
    const float* __restrict__ Wc1, const float* __restrict__ bc1,
    const float* __restrict__ Wc2, const float* __restrict__ bc2,
    const float* __restrict__ lng, const float* __restrict__ lnb,
    const ushort* __restrict__ wbF1, const float* __restrict__ bf1,
    const ushort* __restrict__ wbF2, const float* __restrict__ bf2,
    float* __restrict__ out)
{
    __shared__ __align__(16) ushort xs[64 * LDP];
    __shared__ __align__(16) ushort wsl[128 * LDP];
    const int t = threadIdx.x;
    const int row0 = blockIdx.x * 64;
    const int w = t >> 6, l = t & 63;

    // stage Wf1 early (bf16 direct)
    #pragma unroll
    for (int i = 0; i < 8; ++i) {
        int e = t + i * 256, r = e >> 4, c = (e & 15) * 8;
        uint4 v = *reinterpret_cast<const uint4*>(wbF1 + (size_t)r * 128 + c);
        *reinterpret_cast<uint4*>(wsl + r * LDP + c) = v;
    }

    // ---- phase 0: comb + LayerNorm, wave per row, 16 rows per wave ----
    {
        const int d0 = 2 * l;
        const float g0 = lng[d0], g1 = lng[d0 + 1];
        const float be0 = lnb[d0], be1 = lnb[d0 + 1];
        const float c2v[4] = {Wc2[0], Wc2[1], Wc2[2], Wc2[3]};
        const float b2v = bc2[0];
        for (int i = 0; i < 16; ++i) {
            int rl = w * 16 + i;
            int rrow = row0 + rl;
            int b = rrow >> 12;
            int n = rrow & 4095;
            size_t r = (size_t)rrow;

            ushort2 xv2 = *reinterpret_cast<const ushort2*>(x1b + r * 128 + d0);
            float2 p2 = *reinterpret_cast<const float2*>(pos + (size_t)n * 128 + d0);
            float2 s0 = *reinterpret_cast<const float2*>(S0 + b * 128 + d0);
            float2 s1 = *reinterpret_cast<const float2*>(S1 + b * 128 + d0);
            float cc = p2.y, ss = p2.x;
            float xv[2] = {bf2f(xv2.x), bf2f(xv2.y)};
            float S0a[2] = {s0.x, s0.y}, S1a[2] = {s1.x, s1.y};
            float2 Tv[4];
            #pragma unroll
            for (int h = 0; h < 4; ++h)
                Tv[h] = *reinterpret_cast<const float2*>(T + (b * 4 + h) * 128 + d0);
            float phv[4][2];
            #pragma unroll
            for (int h = 0; h < 4; ++h) {
                unsigned int pu = *reinterpret_cast<const ushort*>(phi8 + r * 512 + h * 128 + d0);
                phv[h][0] = __builtin_amdgcn_cvt_f32_fp8(pu, 0);
                phv[h][1] = __builtin_amdgcn_cvt_f32_fp8(pu, 1);
            }

            float m[2];
            #pragma unroll
            for (int q = 0; q < 2; ++q) {
                float f0 = S0a[q] - xv[q] * cc;
                float f1 = xv[q] * ss - S1a[q];
                float fn = sqrtf(f0 * f0 + f1 * f1);
                float fec = f0 * cc - f1 * ss;
                float inv[4];
                #pragma unroll
                for (int h = 0; h < 4; ++h) {
                    float res = fmaxf(0.f, fminf(1.f, fn - phv[h][q]));
                    float tv = q ? Tv[h].y : Tv[h].x;
                    inv[h] = (tv - res * fec) * (1.f / (float)Nn);
                }
                float comb = b2v;
                #pragma unroll
                for (int h = 0; h < 4; ++h) {
                    float u = bc1[h];
                    #pragma unroll
                    for (int h2 = 0; h2 < 4; ++h2) u += Wc1[h * 4 + h2] * inv[h2];
                    comb += fmaxf(u, 0.f) * c2v[h];
                }
                m[q] = xv[q] + comb;
            }

            float s = m[0] + m[1];
            #pragma unroll
            for (int off = 32; off; off >>= 1) s += __shfl_xor(s, off);
            float mu = s * (1.f / 128.f);
            float e0 = m[0] - mu, e1 = m[1] - mu;
            float v = e0 * e0 + e1 * e1;
            #pragma unroll
            for (int off = 32; off; off >>= 1) v += __shfl_xor(v, off);
            float rstd = rsqrtf(v * (1.f / 128.f) + 1e-6f);
            ushort2 o;
            o.x = f2bf(e0 * rstd * g0 + be0);
            o.y = f2bf(e1 * rstd * g1 + be1);
            *reinterpret_cast<ushort2*>(xs + rl * LDP + d0) = o;
        }
    }
    __syncthreads();

    const int lr = l & 15;
    const int lk = (l >> 4) * 8;

    // ---- phase 1: h1 = relu(mn @ Wf1^T + b1) ----
    f32x4 acc[8];
    #pragma unroll
    for (int cf = 0; cf < 8; ++cf) acc[cf] = f32x4{0.f, 0.f, 0.f, 0.f};
    #pragma unroll
    for (int ks = 0; ks < 4; ++ks) {
        bf16x8 a = *reinterpret_cast<const bf16x8*>(xs + (w * 16 + lr) * LDP + ks * 32 + lk);
        #pragma unroll
        for (int cf = 0; cf < 8; ++cf) {
            bf16x8 b = *reinterpret_cast<const bf16x8*>(wsl + (cf * 16 + lr) * LDP + ks * 32 + lk);
            acc[cf] = __builtin_amdgcn_mfma_f32_16x16x32_bf16(a, b, acc[cf], 0, 0, 0);
        }
    }
    __syncthreads();

    #pragma unroll
    for (int cf = 0; cf < 8; ++cf) {
        int col = cf * 16 + lr;
        float bv = bf1[col];
        #pragma unroll
        for (int reg = 0; reg < 4; ++reg) {
            int rl = w * 16 + (l >> 4) * 4 + reg;
            xs[rl * LDP + col] = f2bf(fmaxf(acc[cf][reg] + bv, 0.f));
        }
    }
    // restage wsl with Wf2 (bf16 direct)
    #pragma unroll
    for (int i = 0; i < 8; ++i) {
        int e = t + i * 256, r = e >> 4, c = (e & 15) * 8;
        uint4 v = *reinterpret_cast<const uint4*>(wbF2 + (size_t)r * 128 + c);
        *reinterpret_cast<uint4*>(wsl + r * LDP + c) = v;
    }
    __syncthreads();

    // ---- phase 2: out = h1 @ Wf2^T + b2 ----
    #pragma unroll
    for (int cf = 0; cf < 8; ++cf) acc[cf] = f32x4{0.f, 0.f, 0.f, 0.f};
    #pragma unroll
    for (int ks = 0; ks < 4; ++ks) {
        bf16x8 a = *reinterpret_cast<const bf16x8*>(xs + (w * 16 + lr) * LDP + ks * 32 + lk);
        #pragma unroll
        for (int cf = 0; cf < 8; ++cf) {
            bf16x8 b = *reinterpret_cast<const bf16x8*>(wsl + (cf * 16 + lr) * LDP + ks * 32 + lk);
            acc[cf] = __builtin_amdgcn_mfma_f32_16x16x32_bf16(a, b, acc[cf], 0, 0, 0);
        }
    }
    #pragma unroll
    for (int cf = 0; cf < 8; ++cf) {
        int col = cf * 16 + lr;
        float bv = bf2[col];
        #pragma unroll
        for (int reg = 0; reg < 4; ++reg) {
            int r = row0 + w * 16 + (l >> 4) * 4 + reg;
            out[(size_t)r * 128 + col] = acc[cf][reg] + bv;
        }
    }
}

// ---------------------------------------------------------------------------
extern "C" void kernel_launch(void* const* d_in, const int* in_sizes, int n_in,
                              void* d_out, int out_size, void* d_ws, size_t ws_size,
                              hipStream_t stream)
{
    const float* x    = (const float*)d_in[0];
    const float* pos  = (const float*)d_in[1];
    const float* Wlt  = (const float*)d_in[2];
    const float* Wphi = (const float*)d_in[3];
    const float* bphi = (const float*)d_in[4];
    const float* Wc1  = (const float*)d_in[5];
    const float* bc1  = (const float*)d_in[6];
    const float* Wc2  = (const float*)d_in[7];
    const float* bc2  = (const float*)d_in[8];
    const float* lng  = (const float*)d_in[9];
    const float* lnb  = (const float*)d_in[10];
    const float* Wf1  = (const float*)d_in[11];
    const float* bf1  = (const float*)d_in[12];
    const float* Wf2  = (const float*)d_in[13];
    const float* bf2  = (const float*)d_in[14];

    float* ws = (float*)d_ws;
    ushort* x1b = (ushort*)ws;                     // [BN*128] bf16   8 MB
    float* S0   = ws + 2097152;                    // [1024]
    float* S1   = S0 + 1024;                       // [1024]
    float* T    = S1 + 1024;                       // [4096]
    float* PS   = T + 4096;                        // [512*256]       512 KB
    float* PT   = PS + 131072;                     // [512*512]       1 MB
    unsigned char* phi8 = (unsigned char*)(ws + 2496512);  // [BN*512] fp8  16 MB
    ushort* wbLt  = (ushort*)(ws + 6690816);       // [16384] bf16
    ushort* wbPhi = wbLt + 16384;                  // [65536] bf16
    ushort* wbF1  = wbPhi + 65536;                 // [16384] bf16
    ushort* wbF2  = wbF1 + 16384;                  // [16384] bf16
    float* out  = (float*)d_out;

    k_prep<<<dim3(56), 256, 0, stream>>>(Wlt, Wphi, Wf1, Wf2, wbLt, wbPhi, wbF1, wbF2);
    k_fused1<<<dim3(BN / 64), 256, 0, stream>>>(x, wbLt, wbPhi, bphi, pos, x1b, phi8, PS);
    {
        const ushort* a0 = x1b; const unsigned char* a1 = phi8; const float* a2 = pos;
        const float* a3 = PS; float* a4 = S0; float* a5 = S1; float* a6 = PT; float* a7 = T;
        void* args[] = {&a0, &a1, &a2, &a3, &a4, &a5, &a6, &a7};
        hipLaunchCooperativeKernel((const void*)k_coop_ST, dim3(512), dim3(256),
                                   args, 0, stream);
    }
    k_comb_ffn<<<dim3(BN / 64), 256, 0, stream>>>(x1b, phi8, pos, S0, S1, T,
                                                  Wc1, bc1, Wc2, bc2, lng, lnb,
                                                  wbF1, bf1, wbF2, bf2, out);
}

// Round 10
// 71.849 us; speedup vs baseline: 3.2525x; 3.2525x over previous
//
#include <hip/hip_runtime.h>
#include <hip/hip_bf16.h>

// FourierResistor: B=8, N=4096, d=128, H=4, fp32 in/out.
// sum-minus-self decomposition:
//   f[k,b,n,d]  = S[k,b,d] - xe[k,b,n,d],  S = sum_n xe
//   inv[b,n,h,d]= (T[b,h,d] - rfe[b,n,h,d]) / N,  T = sum_n rfe
// Pipeline (4 dispatches, NO cooperative sync — r9 showed grid.sync costs ~75us):
//   K0 prep   : Wlt,Wphi,Wf1,Wf2 -> bf16 (224 KB, once)
//   K1 fused  : x1b = bf16(x@Wlt^T); S-partials -> PS; xs += pos;
//               phi8 = fp8e4m3((x1+pos)@Wphi^T+b) over 4 col tiles
//   K2 redT   : block-local finalize S from PS (L2-resident) -> LDS;
//               c64==0 blocks write S0/S1 global; PT partials of T
//   K3 combffn: block-local finalize T from PT -> LDS; comb MLP + LN -> LDS
//               -> relu(mn@Wf1^T+b1)@Wf2^T+b2 -> out

#define DEV __device__ __forceinline__

typedef __attribute__((ext_vector_type(8))) short bf16x8;
typedef __attribute__((ext_vector_type(4))) float f32x4;

constexpr int Bb = 8, Nn = 4096;
constexpr int BN = Bb * Nn;     // 32768
constexpr int LDP = 136;        // padded LDS pitch in bf16 elems (272 B)
constexpr int P8  = 144;        // byte pitch for fp8 restage (16B-aligned)

union U8 { ushort u[8]; uint4 v; };

static DEV ushort f2bf(float f) {
    __hip_bfloat16 h = __float2bfloat16(f);
    return *reinterpret_cast<unsigned short*>(&h);
}
static DEV float bf2f(ushort u) {
    return __bfloat162float(*reinterpret_cast<const __hip_bfloat16*>(&u));
}
// native gfx950 OCP-e4m3 converts (1 VALU op each)
static DEV unsigned char f2fp8(float f) {
    return (unsigned char)(__builtin_amdgcn_cvt_pk_fp8_f32(f, f, 0u, false) & 0xff);
}

// ---------------------------------------------------------------------------
// K0: pre-convert weights fp32 -> bf16 (Wlt 16K | Wphi 64K | Wf1 16K | Wf2 16K)
// ---------------------------------------------------------------------------
__global__ __launch_bounds__(256) void k_prep(
    const float* __restrict__ Wlt, const float* __restrict__ Wphi,
    const float* __restrict__ Wf1, const float* __restrict__ Wf2,
    ushort* __restrict__ wbLt, ushort* __restrict__ wbPhi,
    ushort* __restrict__ wbF1, ushort* __restrict__ wbF2)
{
    int bx = blockIdx.x;
    const float* src; ushort* dst; int off;
    if (bx < 8)       { src = Wlt;  dst = wbLt;  off = bx * 2048; }
    else if (bx < 40) { src = Wphi; dst = wbPhi; off = (bx - 8) * 2048; }
    else if (bx < 48) { src = Wf1;  dst = wbF1;  off = (bx - 40) * 2048; }
    else              { src = Wf2;  dst = wbF2;  off = (bx - 48) * 2048; }
    int e = off + threadIdx.x * 8;
    float4 a = *reinterpret_cast<const float4*>(src + e);
    float4 b = *reinterpret_cast<const float4*>(src + e + 4);
    U8 u;
    u.u[0] = f2bf(a.x); u.u[1] = f2bf(a.y); u.u[2] = f2bf(a.z); u.u[3] = f2bf(a.w);
    u.u[4] = f2bf(b.x); u.u[5] = f2bf(b.y); u.u[6] = f2bf(b.z); u.u[7] = f2bf(b.w);
    *reinterpret_cast<uint4*>(dst + e) = u.v;
}

// ---------------------------------------------------------------------------
// K1: fused x-GEMM + S-partials + phi-GEMM. W inputs are pre-converted bf16.
// ---------------------------------------------------------------------------
__global__ __launch_bounds__(256) void k_fused1(
    const float* __restrict__ X, const ushort* __restrict__ wbLt,
    const ushort* __restrict__ wbPhi, const float* __restrict__ bphi,
    const float* __restrict__ pos, ushort* __restrict__ x1b,
    unsigned char* __restrict__ phi8, float* __restrict__ PS)
{
    __shared__ __align__(16) ushort xs[64 * LDP];        // 17408 B
    __shared__ __align__(16) ushort wsl[128 * LDP];      // 34816 B
    __shared__ __align__(16) unsigned char aux[64 * P8]; // 9216 B (red | p8)
    float (*red)[2][128] = reinterpret_cast<float (*)[2][128]>(aux);
    unsigned char* p8 = aux;

    const int t = threadIdx.x;
    const int row0 = blockIdx.x * 64;
    const int w = t >> 6, l = t & 63;
    const int lr = l & 15;
    const int lk = (l >> 4) * 8;

    // ---- stage X tile (f32 -> bf16) ----
    #pragma unroll
    for (int i = 0; i < 4; ++i) {
        int e = t + i * 256, r = e >> 4, c = (e & 15) * 8;
        const float* p = X + (size_t)(row0 + r) * 128 + c;
        float4 a = *reinterpret_cast<const float4*>(p);
        float4 b = *reinterpret_cast<const float4*>(p + 4);
        U8 u;
        u.u[0] = f2bf(a.x); u.u[1] = f2bf(a.y); u.u[2] = f2bf(a.z); u.u[3] = f2bf(a.w);
        u.u[4] = f2bf(b.x); u.u[5] = f2bf(b.y); u.u[6] = f2bf(b.z); u.u[7] = f2bf(b.w);
        *reinterpret_cast<uint4*>(xs + r * LDP + c) = u.v;
    }
    // ---- stage Wlt (bf16, direct copy) ----
    #pragma unroll
    for (int i = 0; i < 8; ++i) {
        int e = t + i * 256, r = e >> 4, c = (e & 15) * 8;
        uint4 v = *reinterpret_cast<const uint4*>(wbLt + (size_t)r * 128 + c);
        *reinterpret_cast<uint4*>(wsl + r * LDP + c) = v;
    }
    __syncthreads();

    // ---- MFMA: x1 = x @ Wlt^T ----
    {
        f32x4 acc[8];
        #pragma unroll
        for (int cf = 0; cf < 8; ++cf) acc[cf] = f32x4{0.f, 0.f, 0.f, 0.f};
        #pragma unroll
        for (int ks = 0; ks < 4; ++ks) {
            bf16x8 a = *reinterpret_cast<const bf16x8*>(xs + (w * 16 + lr) * LDP + ks * 32 + lk);
            #pragma unroll
            for (int cf = 0; cf < 8; ++cf) {
                bf16x8 b = *reinterpret_cast<const bf16x8*>(wsl + (cf * 16 + lr) * LDP + ks * 32 + lk);
                acc[cf] = __builtin_amdgcn_mfma_f32_16x16x32_bf16(a, b, acc[cf], 0, 0, 0);
            }
        }
        __syncthreads();  // xs reads done

        // restage x1 into xs (bf16); C/D layout: col=lane&15, row=(lane>>4)*4+reg
        #pragma unroll
        for (int cf = 0; cf < 8; ++cf) {
            int col = cf * 16 + lr;
            #pragma unroll
            for (int reg = 0; reg < 4; ++reg) {
                int rl = w * 16 + (l >> 4) * 4 + reg;
                xs[rl * LDP + col] = f2bf(acc[cf][reg]);
            }
        }
    }
    __syncthreads();

    // ---- phase A: store x1b (coalesced) + S-partial column reduce from xs ----
    #pragma unroll
    for (int i = 0; i < 4; ++i) {
        int e = t + i * 256, r = e >> 4, c = (e & 15) * 8;
        uint4 v = *reinterpret_cast<const uint4*>(xs + r * LDP + c);
        *reinterpret_cast<uint4*>(x1b + (size_t)(row0 + r) * 128 + c) = v;
    }
    {
        int c2 = t & 63, g = t >> 6;
        float a0e = 0.f, a1e = 0.f, a0o = 0.f, a1o = 0.f;
        #pragma unroll 4
        for (int i = 0; i < 16; ++i) {
            int r = g * 16 + i;
            int n = (row0 + r) & (Nn - 1);
            unsigned int v = *reinterpret_cast<const unsigned int*>(xs + r * LDP + 2 * c2);
            float lo = bf2f((ushort)(v & 0xffff));
            float hi = bf2f((ushort)(v >> 16));
            float2 p = *reinterpret_cast<const float2*>(pos + (size_t)n * 128 + 2 * c2);
            a0e += lo * p.y; a1e += lo * p.x;   // cols 2c2, 2c2+1 share (s,c)
            a0o += hi * p.y; a1o += hi * p.x;
        }
        red[g][0][2 * c2] = a0e; red[g][0][2 * c2 + 1] = a0o;
        red[g][1][2 * c2] = a1e; red[g][1][2 * c2 + 1] = a1o;
    }
    __syncthreads();

    // ---- phase B: PS write (reads red) + xs += pos (in place) ----
    {
        int half = t >> 7, col = t & 127;
        float s = red[0][half][col] + red[1][half][col] + red[2][half][col] + red[3][half][col];
        PS[(size_t)blockIdx.x * 256 + t] = s;
    }
    #pragma unroll
    for (int i = 0; i < 4; ++i) {
        int e = t + i * 256, r = e >> 4, c = (e & 15) * 8;
        U8 u;
        u.v = *reinterpret_cast<const uint4*>(xs + r * LDP + c);
        int n = (row0 + r) & (Nn - 1);
        const float* q = pos + (size_t)n * 128 + c;
        float4 pa = *reinterpret_cast<const float4*>(q);
        float4 pb = *reinterpret_cast<const float4*>(q + 4);
        u.u[0] = f2bf(bf2f(u.u[0]) + pa.x);
        u.u[1] = f2bf(bf2f(u.u[1]) + pa.y);
        u.u[2] = f2bf(bf2f(u.u[2]) + pa.z);
        u.u[3] = f2bf(bf2f(u.u[3]) + pa.w);
        u.u[4] = f2bf(bf2f(u.u[4]) + pb.x);
        u.u[5] = f2bf(bf2f(u.u[5]) + pb.y);
        u.u[6] = f2bf(bf2f(u.u[6]) + pb.z);
        u.u[7] = f2bf(bf2f(u.u[7]) + pb.w);
        *reinterpret_cast<uint4*>(xs + r * LDP + c) = u.v;
    }

    // ---- phi loop: 4 col tiles of Wphi (bf16); p8 aliases red (red dead) ----
    for (int jt = 0; jt < 4; ++jt) {
        __syncthreads();   // wsl free / p8 of jt-1 encoded / phase B done
        {
            const ushort* Wt = wbPhi + (size_t)jt * 128 * 128;
            #pragma unroll
            for (int i = 0; i < 8; ++i) {
                int e = t + i * 256, r = e >> 4, c = (e & 15) * 8;
                uint4 v = *reinterpret_cast<const uint4*>(Wt + (size_t)r * 128 + c);
                *reinterpret_cast<uint4*>(wsl + r * LDP + c) = v;
            }
            if (jt > 0) {
                #pragma unroll
                for (int i = 0; i < 2; ++i) {
                    int e = t + i * 256, r = e >> 3, c = (e & 7) * 16;
                    uint4 v = *reinterpret_cast<const uint4*>(p8 + r * P8 + c);
                    *reinterpret_cast<uint4*>(phi8 + (size_t)(row0 + r) * 512 + (jt - 1) * 128 + c) = v;
                }
            }
        }
        __syncthreads();

        f32x4 acc[8];
        #pragma unroll
        for (int cf = 0; cf < 8; ++cf) acc[cf] = f32x4{0.f, 0.f, 0.f, 0.f};
        #pragma unroll
        for (int ks = 0; ks < 4; ++ks) {
            bf16x8 a = *reinterpret_cast<const bf16x8*>(xs + (w * 16 + lr) * LDP + ks * 32 + lk);
            #pragma unroll
            for (int cf = 0; cf < 8; ++cf) {
                bf16x8 b = *reinterpret_cast<const bf16x8*>(wsl + (cf * 16 + lr) * LDP + ks * 32 + lk);
                acc[cf] = __builtin_amdgcn_mfma_f32_16x16x32_bf16(a, b, acc[cf], 0, 0, 0);
            }
        }
        #pragma unroll
        for (int cf = 0; cf < 8; ++cf) {
            int col = cf * 16 + lr;
            float bv = bphi[jt * 128 + col];
            #pragma unroll
            for (int reg = 0; reg < 4; ++reg) {
                int rl = w * 16 + (l >> 4) * 4 + reg;
                p8[rl * P8 + col] = f2fp8(acc[cf][reg] + bv);
            }
        }
    }
    __syncthreads();
    #pragma unroll
    for (int i = 0; i < 2; ++i) {
        int e = t + i * 256, r = e >> 3, c = (e & 7) * 16;
        uint4 v = *reinterpret_cast<const uint4*>(p8 + r * P8 + c);
        *reinterpret_cast<uint4*>(phi8 + (size_t)(row0 + r) * 512 + 3 * 128 + c) = v;
    }
}

// ---------------------------------------------------------------------------
// K2: block-local S finalize (PS is L2-resident) + PT partials of T.
// 512 blocks; blocks with c64==0 also write S0/S1 global for K3.
// ---------------------------------------------------------------------------
__global__ __launch_bounds__(256) void k_reduceT2(
    const ushort* __restrict__ x1b, const unsigned char* __restrict__ phi8,
    const float* __restrict__ pos, const float* __restrict__ PS,
    float* __restrict__ S0, float* __restrict__ S1, float* __restrict__ PT)
{
    int b = blockIdx.x >> 6, c64 = blockIdx.x & 63;

    // finalize S for this batch into LDS (64 KB of L2-resident PS reads)
    __shared__ float Sld[256];
    {
        const float* base = PS + (size_t)b * 64 * 256 + threadIdx.x;
        float s = 0.f;
        #pragma unroll 8
        for (int c = 0; c < 64; ++c) s += base[c * 256];
        Sld[threadIdx.x] = s;
        if (c64 == 0) {
            if (threadIdx.x < 128) S0[b * 128 + threadIdx.x] = s;
            else                   S1[b * 128 + (threadIdx.x - 128)] = s;
        }
    }
    __syncthreads();

    int rr = threadIdx.x >> 5, d0 = (threadIdx.x & 31) * 4;
    float S0a[4] = {Sld[d0], Sld[d0 + 1], Sld[d0 + 2], Sld[d0 + 3]};
    float S1a[4] = {Sld[128 + d0], Sld[128 + d0 + 1], Sld[128 + d0 + 2], Sld[128 + d0 + 3]};
    float acc[4][4];
    #pragma unroll
    for (int h = 0; h < 4; ++h)
        #pragma unroll
        for (int j = 0; j < 4; ++j) acc[h][j] = 0.f;

    #pragma unroll 2
    for (int i = 0; i < 8; ++i) {
        int n = c64 * 64 + i * 8 + rr;
        size_t r = (size_t)b * Nn + n;
        ushort4 xv4 = *reinterpret_cast<const ushort4*>(x1b + r * 128 + d0);
        float4 p = *reinterpret_cast<const float4*>(pos + (size_t)n * 128 + d0);
        float xv[4] = {bf2f(xv4.x), bf2f(xv4.y), bf2f(xv4.z), bf2f(xv4.w)};
        float cc[4] = {p.y, p.y, p.w, p.w};
        float ss[4] = {p.x, p.x, p.z, p.z};
        float fec[4], fn[4];
        #pragma unroll
        for (int j = 0; j < 4; ++j) {
            float f0 = S0a[j] - xv[j] * cc[j];
            float f1 = xv[j] * ss[j] - S1a[j];
            fn[j] = sqrtf(f0 * f0 + f1 * f1);
            fec[j] = f0 * cc[j] - f1 * ss[j];
        }
        #pragma unroll
        for (int h = 0; h < 4; ++h) {
            unsigned int pv = *reinterpret_cast<const unsigned int*>(phi8 + r * 512 + h * 128 + d0);
            float ph0 = __builtin_amdgcn_cvt_f32_fp8(pv, 0);
            float ph1 = __builtin_amdgcn_cvt_f32_fp8(pv, 1);
            float ph2 = __builtin_amdgcn_cvt_f32_fp8(pv, 2);
            float ph3 = __builtin_amdgcn_cvt_f32_fp8(pv, 3);
            acc[h][0] += fmaxf(0.f, fminf(1.f, fn[0] - ph0)) * fec[0];
            acc[h][1] += fmaxf(0.f, fminf(1.f, fn[1] - ph1)) * fec[1];
            acc[h][2] += fmaxf(0.f, fminf(1.f, fn[2] - ph2)) * fec[2];
            acc[h][3] += fmaxf(0.f, fminf(1.f, fn[3] - ph3)) * fec[3];
        }
    }
    __shared__ float red[8][512];
    #pragma unroll
    for (int h = 0; h < 4; ++h)
        #pragma unroll
        for (int j = 0; j < 4; ++j) red[rr][h * 128 + d0 + j] = acc[h][j];
    __syncthreads();
    int tt = threadIdx.x;
    #pragma unroll
    for (int q = 0; q < 2; ++q) {
        int idx = tt + q * 256;
        float s = 0.f;
        #pragma unroll
        for (int k = 0; k < 8; ++k) s += red[k][idx];
        PT[(size_t)blockIdx.x * 512 + idx] = s;
    }
}

// ---------------------------------------------------------------------------
// K3: block-local T finalize (PT is L2-resident) + comb+LN+FFN.
// ---------------------------------------------------------------------------
__global__ __launch_bounds__(256) void k_comb_ffn(
    const ushort* __restrict__ x1b, const unsigned char* __restrict__ phi8,
    const float* __restrict__ pos, const float* __restrict__ S0,
    const float* __restrict__ S1, const float* __restrict__ PT,
    const float* __restrict__ Wc1, const float* __restrict__ bc1,
    const float* __restrict__ Wc2, const float* __restrict__ bc2,
    const float* __restrict__ lng, const float* __restrict__ lnb,
    const ushort* __restrict__ wbF1, const float* __restrict__ bf1,
    const ushort* __restrict__ wbF2, const float* __restrict__ bf2,
    float* __restrict__ out)
{
    __shared__ __align__(16) ushort xs[64 * LDP];
    __shared__ __align__(16) ushort wsl[128 * LDP];
    __shared__ float Tld[512];
    const int t = threadIdx.x;
    const int row0 = blockIdx.x * 64;
    const int w = t >> 6, l = t & 63;
    const int bb = row0 >> 12;

    // finalize T for this batch into LDS (128 KB of L2-resident PT reads)
    {
        const float* base = PT + (size_t)bb * 64 * 512;
        #pragma unroll
        for (int q = 0; q < 2; ++q) {
            int idx = t + q * 256;
            float s = 0.f;
            #pragma unroll 8
            for (int c = 0; c < 64; ++c) s += base[c * 512 + idx];
            Tld[idx] = s;
        }
    }

    // stage Wf1 (bf16 direct)
    #pragma unroll
    for (int i = 0; i < 8; ++i) {
        int e = t + i * 256, r = e >> 4, c = (e & 15) * 8;
        uint4 v = *reinterpret_cast<const uint4*>(wbF1 + (size_t)r * 128 + c);
        *reinterpret_cast<uint4*>(wsl + r * LDP + c) = v;
    }
    __syncthreads();   // Tld ready

    // ---- phase 0: comb + LayerNorm, wave per row, 16 rows per wave ----
    {
        const int d0 = 2 * l;
        const float g0 = lng[d0], g1 = lng[d0 + 1];
        const float be0 = lnb[d0], be1 = lnb[d0 + 1];
        const float c2v[4] = {Wc2[0], Wc2[1], Wc2[2], Wc2[3]};
        const float b2v = bc2[0];
        float2 s0 = *reinterpret_cast<const float2*>(S0 + bb * 128 + d0);
        float2 s1 = *reinterpret_cast<const float2*>(S1 + bb * 128 + d0);
        float S0a[2] = {s0.x, s0.y}, S1a[2] = {s1.x, s1.y};
        float Tv[4][2];
        #pragma unroll
        for (int h = 0; h < 4; ++h) { Tv[h][0] = Tld[h * 128 + d0]; Tv[h][1] = Tld[h * 128 + d0 + 1]; }

        for (int i = 0; i < 16; ++i) {
            int rl = w * 16 + i;
            int rrow = row0 + rl;
            int n = rrow & 4095;
            size_t r = (size_t)rrow;

            ushort2 xv2 = *reinterpret_cast<const ushort2*>(x1b + r * 128 + d0);
            float2 p2 = *reinterpret_cast<const float2*>(pos + (size_t)n * 128 + d0);
            float cc = p2.y, ss = p2.x;
            float xv[2] = {bf2f(xv2.x), bf2f(xv2.y)};
            float phv[4][2];
            #pragma unroll
            for (int h = 0; h < 4; ++h) {
                unsigned int pu = *reinterpret_cast<const ushort*>(phi8 + r * 512 + h * 128 + d0);
                phv[h][0] = __builtin_amdgcn_cvt_f32_fp8(pu, 0);
                phv[h][1] = __builtin_amdgcn_cvt_f32_fp8(pu, 1);
            }

            float m[2];
            #pragma unroll
            for (int q = 0; q < 2; ++q) {
                float f0 = S0a[q] - xv[q] * cc;
                float f1 = xv[q] * ss - S1a[q];
                float fn = sqrtf(f0 * f0 + f1 * f1);
                float fec = f0 * cc - f1 * ss;
                float inv[4];
                #pragma unroll
                for (int h = 0; h < 4; ++h) {
                    float res = fmaxf(0.f, fminf(1.f, fn - phv[h][q]));
                    inv[h] = (Tv[h][q] - res * fec) * (1.f / (float)Nn);
                }
                float comb = b2v;
                #pragma unroll
                for (int h = 0; h < 4; ++h) {
                    float u = bc1[h];
                    #pragma unroll
                    for (int h2 = 0; h2 < 4; ++h2) u += Wc1[h * 4 + h2] * inv[h2];
                    comb += fmaxf(u, 0.f) * c2v[h];
                }
                m[q] = xv[q] + comb;
            }

            float s = m[0] + m[1];
            #pragma unroll
            for (int off = 32; off; off >>= 1) s += __shfl_xor(s, off);
            float mu = s * (1.f / 128.f);
            float e0 = m[0] - mu, e1 = m[1] - mu;
            float v = e0 * e0 + e1 * e1;
            #pragma unroll
            for (int off = 32; off; off >>= 1) v += __shfl_xor(v, off);
            float rstd = rsqrtf(v * (1.f / 128.f) + 1e-6f);
            ushort2 o;
            o.x = f2bf(e0 * rstd * g0 + be0);
            o.y = f2bf(e1 * rstd * g1 + be1);
            *reinterpret_cast<ushort2*>(xs + rl * LDP + d0) = o;
        }
    }
    __syncthreads();

    const int lr = l & 15;
    const int lk = (l >> 4) * 8;

    // ---- phase 1: h1 = relu(mn @ Wf1^T + b1) ----
    f32x4 acc[8];
    #pragma unroll
    for (int cf = 0; cf < 8; ++cf) acc[cf] = f32x4{0.f, 0.f, 0.f, 0.f};
    #pragma unroll
    for (int ks = 0; ks < 4; ++ks) {
        bf16x8 a = *reinterpret_cast<const bf16x8*>(xs + (w * 16 + lr) * LDP + ks * 32 + lk);
        #pragma unroll
        for (int cf = 0; cf < 8; ++cf) {
            bf16x8 b = *reinterpret_cast<const bf16x8*>(wsl + (cf * 16 + lr) * LDP + ks * 32 + lk);
            acc[cf] = __builtin_amdgcn_mfma_f32_16x16x32_bf16(a, b, acc[cf], 0, 0, 0);
        }
    }
    __syncthreads();

    #pragma unroll
    for (int cf = 0; cf < 8; ++cf) {
        int col = cf * 16 + lr;
        float bv = bf1[col];
        #pragma unroll
        for (int reg = 0; reg < 4; ++reg) {
            int rl = w * 16 + (l >> 4) * 4 + reg;
            xs[rl * LDP + col] = f2bf(fmaxf(acc[cf][reg] + bv, 0.f));
        }
    }
    // restage wsl with Wf2 (bf16 direct)
    #pragma unroll
    for (int i = 0; i < 8; ++i) {
        int e = t + i * 256, r = e >> 4, c = (e & 15) * 8;
        uint4 v = *reinterpret_cast<const uint4*>(wbF2 + (size_t)r * 128 + c);
        *reinterpret_cast<uint4*>(wsl + r * LDP + c) = v;
    }
    __syncthreads();

    // ---- phase 2: out = h1 @ Wf2^T + b2 ----
    #pragma unroll
    for (int cf = 0; cf < 8; ++cf) acc[cf] = f32x4{0.f, 0.f, 0.f, 0.f};
    #pragma unroll
    for (int ks = 0; ks < 4; ++ks) {
        bf16x8 a = *reinterpret_cast<const bf16x8*>(xs + (w * 16 + lr) * LDP + ks * 32 + lk);
        #pragma unroll
        for (int cf = 0; cf < 8; ++cf) {
            bf16x8 b = *reinterpret_cast<const bf16x8*>(wsl + (cf * 16 + lr) * LDP + ks * 32 + lk);
            acc[cf] = __builtin_amdgcn_mfma_f32_16x16x32_bf16(a, b, acc[cf], 0, 0, 0);
        }
    }
    #pragma unroll
    for (int cf = 0; cf < 8; ++cf) {
        int col = cf * 16 + lr;
        float bv = bf2[col];
        #pragma unroll
        for (int reg = 0; reg < 4; ++reg) {
            int r = row0 + w * 16 + (l >> 4) * 4 + reg;
            out[(size_t)r * 128 + col] = acc[cf][reg] + bv;
        }
    }
}

// ---------------------------------------------------------------------------
extern "C" void kernel_launch(void* const* d_in, const int* in_sizes, int n_in,
                              void* d_out, int out_size, void* d_ws, size_t ws_size,
                              hipStream_t stream)
{
    const float* x    = (const float*)d_in[0];
    const float* pos  = (const float*)d_in[1];
    const float* Wlt  = (const float*)d_in[2];
    const float* Wphi = (const float*)d_in[3];
    const float* bphi = (const float*)d_in[4];
    const float* Wc1  = (const float*)d_in[5];
    const float* bc1  = (const float*)d_in[6];
    const float* Wc2  = (const float*)d_in[7];
    const float* bc2  = (const float*)d_in[8];
    const float* lng  = (const float*)d_in[9];
    const float* lnb  = (const float*)d_in[10];
    const float* Wf1  = (const float*)d_in[11];
    const float* bf1  = (const float*)d_in[12];
    const float* Wf2  = (const float*)d_in[13];
    const float* bf2  = (const float*)d_in[14];

    float* ws = (float*)d_ws;
    ushort* x1b = (ushort*)ws;                     // [BN*128] bf16   8 MB
    float* S0   = ws + 2097152;                    // [1024]
    float* S1   = S0 + 1024;                       // [1024]
    float* PS   = S1 + 1024;                       // [512*256]       512 KB
    float* PT   = PS + 131072;                     // [512*512]       1 MB
    unsigned char* phi8 = (unsigned char*)(ws + 2492416);  // [BN*512] fp8  16 MB
    ushort* wbLt  = (ushort*)(ws + 6686720);       // [16384] bf16
    ushort* wbPhi = wbLt + 16384;                  // [65536] bf16
    ushort* wbF1  = wbPhi + 65536;                 // [16384] bf16
    ushort* wbF2  = wbF1 + 16384;                  // [16384] bf16
    float* out  = (float*)d_out;

    k_prep<<<dim3(56), 256, 0, stream>>>(Wlt, Wphi, Wf1, Wf2, wbLt, wbPhi, wbF1, wbF2);
    k_fused1<<<dim3(BN / 64), 256, 0, stream>>>(x, wbLt, wbPhi, bphi, pos, x1b, phi8, PS);
    k_reduceT2<<<dim3(512), 256, 0, stream>>>(x1b, phi8, pos, PS, S0, S1, PT);
    k_comb_ffn<<<dim3(BN / 64), 256, 0, stream>>>(x1b, phi8, pos, S0, S1, PT,
                                                  Wc1, bc1, Wc2, bc2, lng, lnb,
                                                  wbF1, bf1, wbF2, bf2, out);
}